// Round 2
// baseline (180.440 us; speedup 1.0000x reference)
//
#include <hip/hip_runtime.h>
#include <hip/hip_bf16.h>
#include <cstdint>

// Problem constants: T=512 timesteps/slots, B=64 batch, E=512 embed.
#define TT 512
#define BB 64
#define EE 512

typedef short bf16x8 __attribute__((ext_vector_type(8)));   // 8 bf16 = 4 VGPRs (A/B frag)
typedef float f32x4  __attribute__((ext_vector_type(4)));   // C/D frag

static __device__ __forceinline__ unsigned short f32_to_bf16(float f) {
    unsigned u = __float_as_uint(f);
    u += 0x7fffu + ((u >> 16) & 1u);   // RNE; finite values only
    return (unsigned short)(u >> 16);
}

// ---------------------------------------------------------------------------
// K1: queue strength recurrence via prefix-sum trick.
//   P_i(t): P <- relu(P - u_t); if (t<=i) P += d_t
//   C[t,i,b] = min(P_i(t),1) - min(P_{i-1}(t),1)
// Each thread owns slots (i, i+1) -> 3 shared recurrences, packed uint store.
// Grid: 256 blocks x 64 threads. b -> XCD b%8 (matches K3).
// ---------------------------------------------------------------------------
__global__ __launch_bounds__(64) void queue_coeffs_kernel(
        const float* __restrict__ U, const float* __restrict__ D,
        unsigned short* __restrict__ C) {
    const int id    = blockIdx.x;
    const int xcd   = id & 7;
    const int s     = id >> 3;           // 0..31
    const int b     = xcd + 8 * (s & 7); // b % 8 == xcd
    const int chunk = s >> 3;            // 0..3

    __shared__ float Us[TT];
    __shared__ float Ds[TT];
    for (int t = threadIdx.x; t < TT; t += 64) {
        Us[t] = U[t * BB + b];
        Ds[t] = D[t * BB + b];
    }
    __syncthreads();

    const int i = chunk * 128 + (int)threadIdx.x * 2;   // even slot
    float Pm = 0.f, P0 = 0.f, P1 = 0.f;                 // P_{i-1}, P_i, P_{i+1}
    unsigned int* Crow = (unsigned int*)(C + (size_t)b * TT * TT + i);
    #pragma unroll 4
    for (int t = 0; t < TT; ++t) {
        const float u = Us[t];
        const float d = Ds[t];
        Pm = fmaxf(Pm - u, 0.f);
        P0 = fmaxf(P0 - u, 0.f);
        P1 = fmaxf(P1 - u, 0.f);
        if (t <  i)     Pm += d;
        if (t <= i)     P0 += d;
        if (t <= i + 1) P1 += d;
        const float c0 = fminf(P0, 1.f) - fminf(Pm, 1.f);
        const float c1 = fminf(P1, 1.f) - fminf(P0, 1.f);
        const unsigned int packed =
            (unsigned int)f32_to_bf16(c0) | ((unsigned int)f32_to_bf16(c1) << 16);
        Crow[(size_t)t * (TT / 2)] = packed;
    }
}

// ---------------------------------------------------------------------------
// K2: V[i,b,e] fp32 -> VbT[b][e][i] bf16. Register 4x4 micro-tile transpose:
// coalesced float4 reads, LDS scatter (72-short padded rows), 16B LDS reads,
// 16B global stores. 64i x 64e tiles; b -> XCD b%8.
// Grid: 4096 blocks x 256 threads.
// ---------------------------------------------------------------------------
__global__ __launch_bounds__(256) void transpose_v_kernel(
        const float* __restrict__ V, unsigned short* __restrict__ Vt) {
    const int id   = blockIdx.x;
    const int xcd  = id & 7;
    const int s    = id >> 3;             // 0..511
    const int b    = xcd + 8 * (s >> 6);  // s>>6: 0..7
    const int tile = s & 63;
    const int i0   = (tile & 7) * 64;
    const int e0   = (tile >> 3) * 64;

    __shared__ unsigned short ts[64 * 72];  // [e][i], stride 72 shorts (16B-aligned rows)

    const int t  = threadIdx.x;
    const int i4 = (t >> 4) * 4;   // 0..60
    const int e4 = (t & 15) * 4;   // 0..60

    // Load 4 rows x float4 (coalesced in e), convert+transpose in registers.
    float4 r[4];
    #pragma unroll
    for (int j = 0; j < 4; ++j)
        r[j] = *(const float4*)(V + ((size_t)(i0 + i4 + j) * BB + b) * EE + e0 + e4);

    #pragma unroll
    for (int jj = 0; jj < 4; ++jj) {
        const float v0 = ((const float*)&r[0])[jj];
        const float v1 = ((const float*)&r[1])[jj];
        const float v2 = ((const float*)&r[2])[jj];
        const float v3 = ((const float*)&r[3])[jj];
        uint2 p;
        p.x = (unsigned int)f32_to_bf16(v0) | ((unsigned int)f32_to_bf16(v1) << 16);
        p.y = (unsigned int)f32_to_bf16(v2) | ((unsigned int)f32_to_bf16(v3) << 16);
        *(uint2*)(ts + (e4 + jj) * 72 + i4) = p;   // 8B write along i
    }
    __syncthreads();

    // Read rows of [e][i] vectorized, store 2x16B per thread.
    const int el  = t >> 2;          // 0..63
    const int i16 = (t & 3) * 16;    // 0..48
    unsigned short* dst = Vt + ((size_t)b * EE + e0 + el) * TT + i0 + i16;
    *(uint4*)(dst)     = *(const uint4*)(ts + el * 72 + i16);
    *(uint4*)(dst + 8) = *(const uint4*)(ts + el * 72 + i16 + 8);
}

// ---------------------------------------------------------------------------
// K3: batched NT GEMM, R_b[t,e] = sum_i C_b[t,i] * VbT_b[e,i], bf16 MFMA.
// 64m x 128n tile, BK=32, global_load_lds width-16 staging.
// Grid: 2048 blocks x 256 threads; all 32 tiles of batch b on XCD b%8.
// ---------------------------------------------------------------------------
static __device__ __forceinline__ void gl2lds16(const unsigned short* g,
                                                const unsigned short* l) {
    __builtin_amdgcn_global_load_lds(
        (const __attribute__((address_space(1))) unsigned int*)(uintptr_t)g,
        (__attribute__((address_space(3))) unsigned int*)(unsigned int)(uintptr_t)l,
        16, 0, 0);
}

__global__ __launch_bounds__(256) void gemm_nt_kernel(
        const unsigned short* __restrict__ A,   // [B][T][T]  C_ws (m=t, k=i)
        const unsigned short* __restrict__ Bt,  // [B][E][T]  VbT  (n=e, k=i)
        float* __restrict__ out) {              // [T][B][E]
    const int id   = blockIdx.x;
    const int xcd  = id & 7;
    const int s    = id >> 3;             // 0..255
    const int tile = s & 31;              // 32 tiles per b
    const int b    = xcd + 8 * (s >> 5);  // s>>5: 0..7
    const int m0   = (tile & 7) * 64;     // 8 m-tiles
    const int n0   = (tile >> 3) * 128;   // 4 n-tiles

    const unsigned short* Ab = A  + (size_t)b * TT * TT;
    const unsigned short* Bb = Bt + (size_t)b * EE * TT;

    __shared__ __align__(16) unsigned short As[64 * 32];    // 4 KB
    __shared__ __align__(16) unsigned short Bs[128 * 32];   // 8 KB

    const int tid  = threadIdx.x;
    const int wave = tid >> 6;
    const int lane = tid & 63;
    const int srow = lane >> 2;          // staging row within 16-row wave slab
    const int scol = (lane & 3) * 8;     // staging col (elements)
    const int m_off = (wave >> 1) * 32;
    const int n_off = (wave & 1) * 64;
    const int frow = lane & 15;          // fragment row (m or n)
    const int quad = lane >> 4;          // fragment k-quad

    f32x4 acc[2][4];
    #pragma unroll
    for (int mi = 0; mi < 2; ++mi)
        #pragma unroll
        for (int ni = 0; ni < 4; ++ni)
            acc[mi][ni] = f32x4{0.f, 0.f, 0.f, 0.f};

    for (int k0 = 0; k0 < TT; k0 += 32) {
        // A: 64 rows, 4 waves x 16 rows each
        gl2lds16(Ab + (size_t)(m0 + wave * 16 + srow) * TT + k0 + scol,
                 As + (wave * 16) * 32);
        // B: 128 rows, 2 rounds
        #pragma unroll
        for (int p = 0; p < 2; ++p)
            gl2lds16(Bb + (size_t)(n0 + p * 64 + wave * 16 + srow) * TT + k0 + scol,
                     Bs + (p * 64 + wave * 16) * 32);
        __syncthreads();

        bf16x8 af[2], bfr[4];
        #pragma unroll
        for (int mi = 0; mi < 2; ++mi)
            af[mi] = *(const bf16x8*)(As + (m_off + mi * 16 + frow) * 32 + quad * 8);
        #pragma unroll
        for (int ni = 0; ni < 4; ++ni)
            bfr[ni] = *(const bf16x8*)(Bs + (n_off + ni * 16 + frow) * 32 + quad * 8);

        #pragma unroll
        for (int mi = 0; mi < 2; ++mi)
            #pragma unroll
            for (int ni = 0; ni < 4; ++ni)
                acc[mi][ni] = __builtin_amdgcn_mfma_f32_16x16x32_bf16(
                    af[mi], bfr[ni], acc[mi][ni], 0, 0, 0);
        __syncthreads();
    }

    // Epilogue: C/D layout col=lane&15, row=quad*4+r (m89/m91 verified).
    #pragma unroll
    for (int mi = 0; mi < 2; ++mi) {
        #pragma unroll
        for (int r = 0; r < 4; ++r) {
            const int tt = m0 + m_off + mi * 16 + quad * 4 + r;
            float* orow = out + ((size_t)tt * BB + b) * EE + n0 + n_off + frow;
            #pragma unroll
            for (int ni = 0; ni < 4; ++ni)
                orow[ni * 16] = acc[mi][ni][r];
        }
    }
}

extern "C" void kernel_launch(void* const* d_in, const int* in_sizes, int n_in,
                              void* d_out, int out_size, void* d_ws, size_t ws_size,
                              hipStream_t stream) {
    const float* V = (const float*)d_in[0];   // [T,B,E]
    const float* U = (const float*)d_in[1];   // [T,B]
    const float* D = (const float*)d_in[2];   // [T,B]
    float* out = (float*)d_out;               // [T,B,E]

    unsigned short* C_ws = (unsigned short*)d_ws;                    // [B][T][T] bf16, 32 MB
    unsigned short* VbT  = C_ws + (size_t)BB * TT * TT;              // [B][E][T] bf16, 32 MB

    // K2 first, K1 second: C_ws is freshest in each XCD's L2 when K3 starts.
    transpose_v_kernel<<<dim3(4096), dim3(256), 0, stream>>>(V, VbT);
    queue_coeffs_kernel<<<dim3(256), dim3(64), 0, stream>>>(U, D, C_ws);
    gemm_nt_kernel<<<dim3(2048), dim3(256), 0, stream>>>(C_ws, VbT, out);
}

// Round 3
// 152.782 us; speedup vs baseline: 1.1810x; 1.1810x over previous
//
#include <hip/hip_runtime.h>
#include <hip/hip_bf16.h>
#include <cstdint>

// Problem constants: T=512 timesteps/slots, B=64 batch, E=512 embed.
#define TT 512
#define BB 64
#define EE 512

typedef short bf16x8 __attribute__((ext_vector_type(8)));   // 8 bf16 = 4 VGPRs (A/B frag)
typedef float f32x4  __attribute__((ext_vector_type(4)));   // C/D frag

static __device__ __forceinline__ unsigned short f32_to_bf16(float f) {
    unsigned u = __float_as_uint(f);
    u += 0x7fffu + ((u >> 16) & 1u);   // RNE; finite values only
    return (unsigned short)(u >> 16);
}

// ---------------------------------------------------------------------------
// K0: per-batch scan. Closed form of the queue recurrence:
//   Q(t) = relu(Q(t-1) - u_t) + d_t   (always-push recurrence)
//   CU(t) = sum_{tau<=t} u_tau
//   R(t)  = Q(t) + CU(t)
// Then P_i(t) = relu(R_i - CU_t) for i<=t (and = Q(t) for i>=t).
// Wave-parallel via max-plus composition: step map x -> max(x+a, b),
// (a,b) = (d-u, d); compose g∘f = (a_f+a_g, max(b_f+a_g, b_g)).
// Grid: 64 blocks (one per b) x 64 threads; lane owns 8 consecutive t.
// ---------------------------------------------------------------------------
__global__ __launch_bounds__(64) void scan_kernel(
        const float* __restrict__ U, const float* __restrict__ D,
        float* __restrict__ Rout, float* __restrict__ CUout) {
    const int b    = blockIdx.x;
    const int lane = threadIdx.x;

    float u[8], d[8];
    #pragma unroll
    for (int j = 0; j < 8; ++j) {
        u[j] = U[(lane * 8 + j) * BB + b];
        d[j] = D[(lane * 8 + j) * BB + b];
    }

    // Segment composition (earlier steps applied first).
    float A = 0.f, Bv = -1e30f, S = 0.f;
    #pragma unroll
    for (int j = 0; j < 8; ++j) {
        const float a = d[j] - u[j];
        Bv = fmaxf(Bv + a, d[j]);
        A += a;
        S += u[j];
    }

    // Inclusive non-commutative scan across 64 lanes.
    #pragma unroll
    for (int off = 1; off < 64; off <<= 1) {
        const float Ap = __shfl_up(A, off);
        const float Bp = __shfl_up(Bv, off);
        const float Sp = __shfl_up(S, off);
        if (lane >= off) {
            Bv = fmaxf(Bp + A, Bv);   // prev first, then cur (uses old A)
            A  = A + Ap;
            S  = S + Sp;
        }
    }

    // Exclusive prefix for this lane's segment start.
    float Aex = __shfl_up(A, 1), Bex = __shfl_up(Bv, 1), Sex = __shfl_up(S, 1);
    if (lane == 0) { Aex = 0.f; Bex = -1e30f; Sex = 0.f; }
    float Q  = fmaxf(Aex, Bex);   // apply exclusive map to x0 = 0
    float cu = Sex;

    float rv[8], cv[8];
    #pragma unroll
    for (int j = 0; j < 8; ++j) {
        cu += u[j];
        Q = fmaxf(Q - u[j], 0.f) + d[j];
        rv[j] = Q + cu;
        cv[j] = cu;
    }
    float* rp = Rout  + b * TT + lane * 8;
    float* cp = CUout + b * TT + lane * 8;
    *(float4*)(rp)     = make_float4(rv[0], rv[1], rv[2], rv[3]);
    *(float4*)(rp + 4) = make_float4(rv[4], rv[5], rv[6], rv[7]);
    *(float4*)(cp)     = make_float4(cv[0], cv[1], cv[2], cv[3]);
    *(float4*)(cp + 4) = make_float4(cv[4], cv[5], cv[6], cv[7]);
}

// ---------------------------------------------------------------------------
// K1: C-fill from closed form. C[b][t][i] = Pv_i - Pv_{i-1} for i<=t else 0,
// Pv_i = min(relu(R_i - CU_t), 1), Pv_{-1} = 0.
// Only the trapezoid i < (t/64+1)*64 is written (GEMM reads exactly that).
// Grid: 512 blocks (b x t-tile, XCD-swizzled) x 256 threads.
// Thread (r,q): row t = tt*64+r, chunks cc = q,q+4,... of 8 i each ->
// 4 lanes per row write 64 B contiguous per sweep.
// ---------------------------------------------------------------------------
__global__ __launch_bounds__(256) void cfill_kernel(
        const float* __restrict__ R, const float* __restrict__ CU,
        unsigned short* __restrict__ C) {
    const int id  = blockIdx.x;
    const int xcd = id & 7;
    const int s   = id >> 3;            // 0..63
    const int b   = xcd + 8 * (s & 7);  // b % 8 == xcd (matches gemm)
    const int tt  = s >> 3;             // 0..7 t-tile
    const int NC  = (tt + 1) * 8;       // chunks of 8 per row

    const int r = threadIdx.x >> 2;     // 0..63 row in tile
    const int q = threadIdx.x & 3;
    const int t = tt * 64 + r;
    const float cu = CU[b * TT + t];
    const float* Rb = R + b * TT;
    unsigned short* Crow = C + (size_t)b * TT * TT + (size_t)t * TT;

    for (int cc = q; cc < NC; cc += 4) {
        const int i0 = cc * 8;
        const float4 ra = *(const float4*)(Rb + i0);
        const float4 rb = *(const float4*)(Rb + i0 + 4);
        const float rm1 = (i0 == 0) ? 0.f : Rb[i0 - 1];
        float rv[8] = {ra.x, ra.y, ra.z, ra.w, rb.x, rb.y, rb.z, rb.w};

        float pv_prev = fminf(fmaxf(rm1 - cu, 0.f), 1.f);
        unsigned short cb[8];
        #pragma unroll
        for (int j = 0; j < 8; ++j) {
            const float pv = fminf(fmaxf(rv[j] - cu, 0.f), 1.f);
            const float c = (i0 + j <= t) ? (pv - pv_prev) : 0.f;
            cb[j] = f32_to_bf16(c);
            pv_prev = pv;
        }
        uint4 p;
        p.x = (unsigned)cb[0] | ((unsigned)cb[1] << 16);
        p.y = (unsigned)cb[2] | ((unsigned)cb[3] << 16);
        p.z = (unsigned)cb[4] | ((unsigned)cb[5] << 16);
        p.w = (unsigned)cb[6] | ((unsigned)cb[7] << 16);
        *(uint4*)(Crow + i0) = p;
    }
}

// ---------------------------------------------------------------------------
// K2: V[i,b,e] fp32 -> VbT[b][e][i] bf16 (register micro-tile transpose).
// Grid: 4096 blocks x 256 threads; b -> XCD b%8.
// ---------------------------------------------------------------------------
__global__ __launch_bounds__(256) void transpose_v_kernel(
        const float* __restrict__ V, unsigned short* __restrict__ Vt) {
    const int id   = blockIdx.x;
    const int xcd  = id & 7;
    const int s    = id >> 3;
    const int b    = xcd + 8 * (s >> 6);
    const int tile = s & 63;
    const int i0   = (tile & 7) * 64;
    const int e0   = (tile >> 3) * 64;

    __shared__ unsigned short ts[64 * 72];

    const int t  = threadIdx.x;
    const int i4 = (t >> 4) * 4;
    const int e4 = (t & 15) * 4;

    float4 r[4];
    #pragma unroll
    for (int j = 0; j < 4; ++j)
        r[j] = *(const float4*)(V + ((size_t)(i0 + i4 + j) * BB + b) * EE + e0 + e4);

    #pragma unroll
    for (int jj = 0; jj < 4; ++jj) {
        const float v0 = ((const float*)&r[0])[jj];
        const float v1 = ((const float*)&r[1])[jj];
        const float v2 = ((const float*)&r[2])[jj];
        const float v3 = ((const float*)&r[3])[jj];
        uint2 p;
        p.x = (unsigned)f32_to_bf16(v0) | ((unsigned)f32_to_bf16(v1) << 16);
        p.y = (unsigned)f32_to_bf16(v2) | ((unsigned)f32_to_bf16(v3) << 16);
        *(uint2*)(ts + (e4 + jj) * 72 + i4) = p;
    }
    __syncthreads();

    const int el  = t >> 2;
    const int i16 = (t & 3) * 16;
    unsigned short* dst = Vt + ((size_t)b * EE + e0 + el) * TT + i0 + i16;
    *(uint4*)(dst)     = *(const uint4*)(ts + el * 72 + i16);
    *(uint4*)(dst + 8) = *(const uint4*)(ts + el * 72 + i16 + 8);
}

// ---------------------------------------------------------------------------
// K3: batched NT GEMM with TRIANGULAR K-loop: tile m0 only needs k < m0+64.
// 64m x 128n, BK=32, global_load_lds width-16. Grid 2048 x 256, XCD swizzle.
// ---------------------------------------------------------------------------
static __device__ __forceinline__ void gl2lds16(const unsigned short* g,
                                                const unsigned short* l) {
    __builtin_amdgcn_global_load_lds(
        (const __attribute__((address_space(1))) unsigned int*)(uintptr_t)g,
        (__attribute__((address_space(3))) unsigned int*)(unsigned int)(uintptr_t)l,
        16, 0, 0);
}

__global__ __launch_bounds__(256) void gemm_nt_kernel(
        const unsigned short* __restrict__ A,   // [B][T][T]  C_ws (m=t, k=i)
        const unsigned short* __restrict__ Bt,  // [B][E][T]  VbT  (n=e, k=i)
        float* __restrict__ out) {              // [T][B][E]
    const int id   = blockIdx.x;
    const int xcd  = id & 7;
    const int s    = id >> 3;
    const int tile = s & 31;
    const int b    = xcd + 8 * (s >> 5);
    const int mi_t = tile & 7;
    const int m0   = mi_t * 64;
    const int n0   = (tile >> 3) * 128;
    const int kiters = (mi_t << 1) + 2;   // k < m0 + 64; C[t,i]=0 for i>t

    const unsigned short* Ab = A  + (size_t)b * TT * TT;
    const unsigned short* Bb = Bt + (size_t)b * EE * TT;

    __shared__ __align__(16) unsigned short As[64 * 32];
    __shared__ __align__(16) unsigned short Bs[128 * 32];

    const int tid  = threadIdx.x;
    const int wave = tid >> 6;
    const int lane = tid & 63;
    const int srow = lane >> 2;
    const int scol = (lane & 3) * 8;
    const int m_off = (wave >> 1) * 32;
    const int n_off = (wave & 1) * 64;
    const int frow = lane & 15;
    const int quad = lane >> 4;

    f32x4 acc[2][4];
    #pragma unroll
    for (int mi = 0; mi < 2; ++mi)
        #pragma unroll
        for (int ni = 0; ni < 4; ++ni)
            acc[mi][ni] = f32x4{0.f, 0.f, 0.f, 0.f};

    for (int kk = 0; kk < kiters; ++kk) {
        const int k0 = kk * 32;
        gl2lds16(Ab + (size_t)(m0 + wave * 16 + srow) * TT + k0 + scol,
                 As + (wave * 16) * 32);
        #pragma unroll
        for (int p = 0; p < 2; ++p)
            gl2lds16(Bb + (size_t)(n0 + p * 64 + wave * 16 + srow) * TT + k0 + scol,
                     Bs + (p * 64 + wave * 16) * 32);
        __syncthreads();

        bf16x8 af[2], bfr[4];
        #pragma unroll
        for (int mi = 0; mi < 2; ++mi)
            af[mi] = *(const bf16x8*)(As + (m_off + mi * 16 + frow) * 32 + quad * 8);
        #pragma unroll
        for (int ni = 0; ni < 4; ++ni)
            bfr[ni] = *(const bf16x8*)(Bs + (n_off + ni * 16 + frow) * 32 + quad * 8);

        #pragma unroll
        for (int mi = 0; mi < 2; ++mi)
            #pragma unroll
            for (int ni = 0; ni < 4; ++ni)
                acc[mi][ni] = __builtin_amdgcn_mfma_f32_16x16x32_bf16(
                    af[mi], bfr[ni], acc[mi][ni], 0, 0, 0);
        __syncthreads();
    }

    #pragma unroll
    for (int mi = 0; mi < 2; ++mi) {
        #pragma unroll
        for (int r = 0; r < 4; ++r) {
            const int tt = m0 + m_off + mi * 16 + quad * 4 + r;
            float* orow = out + ((size_t)tt * BB + b) * EE + n0 + n_off + frow;
            #pragma unroll
            for (int ni = 0; ni < 4; ++ni)
                orow[ni * 16] = acc[mi][ni][r];
        }
    }
}

extern "C" void kernel_launch(void* const* d_in, const int* in_sizes, int n_in,
                              void* d_out, int out_size, void* d_ws, size_t ws_size,
                              hipStream_t stream) {
    const float* V = (const float*)d_in[0];   // [T,B,E]
    const float* U = (const float*)d_in[1];   // [T,B]
    const float* D = (const float*)d_in[2];   // [T,B]
    float* out = (float*)d_out;               // [T,B,E]

    unsigned short* C_ws = (unsigned short*)d_ws;                    // 32 MB
    unsigned short* VbT  = C_ws + (size_t)BB * TT * TT;              // 32 MB
    float* R_ws  = (float*)(VbT + (size_t)BB * EE * TT);             // 128 KB
    float* CU_ws = R_ws + BB * TT;                                   // 128 KB

    scan_kernel<<<dim3(BB), dim3(64), 0, stream>>>(U, D, R_ws, CU_ws);
    transpose_v_kernel<<<dim3(4096), dim3(256), 0, stream>>>(V, VbT);
    cfill_kernel<<<dim3(512), dim3(256), 0, stream>>>(R_ws, CU_ws, C_ws);
    gemm_nt_kernel<<<dim3(2048), dim3(256), 0, stream>>>(C_ws, VbT, out);
}

// Round 4
// 137.046 us; speedup vs baseline: 1.3166x; 1.1148x over previous
//
#include <hip/hip_runtime.h>
#include <hip/hip_bf16.h>
#include <cstdint>

// Problem constants: T=512 timesteps/slots, B=64 batch, E=512 embed.
#define TT 512
#define BB 64
#define EE 512

typedef short bf16x8 __attribute__((ext_vector_type(8)));   // 8 bf16 = 4 VGPRs (A/B frag)
typedef float f32x4  __attribute__((ext_vector_type(4)));   // C/D frag

// Round-half-up bf16 pack of (a -> low16, b -> high16). Differs from RNE only
// at exact ties (half-ulp); error magnitude identical.
static __device__ __forceinline__ unsigned int pack_bf16(float a, float b) {
    const unsigned ua = __float_as_uint(a) + 0x8000u;
    const unsigned ub = __float_as_uint(b) + 0x8000u;
    return (ua >> 16) | (ub & 0xffff0000u);
}

// ---------------------------------------------------------------------------
// K0: per-batch scan. Closed form of the queue recurrence:
//   Q(t) = relu(Q(t-1) - u_t) + d_t,  CU(t) = sum u,  R(t) = Q(t) + CU(t)
// Then P_i(t) = relu(R_i - CU_t) for i<=t and
//   C[t,i] = min(relu(R_i-CU_t),1) - min(relu(R_{i-1}-CU_t),1)  (0 for i>t).
// Wave-parallel max-plus scan; lane owns 8 consecutive t.
// Grid: 64 blocks x 64 threads.
// ---------------------------------------------------------------------------
__global__ __launch_bounds__(64) void scan_kernel(
        const float* __restrict__ U, const float* __restrict__ D,
        float* __restrict__ Rout, float* __restrict__ CUout) {
    const int b    = blockIdx.x;
    const int lane = threadIdx.x;

    float u[8], d[8];
    #pragma unroll
    for (int j = 0; j < 8; ++j) {
        u[j] = U[(lane * 8 + j) * BB + b];
        d[j] = D[(lane * 8 + j) * BB + b];
    }

    float A = 0.f, Bv = -1e30f, S = 0.f;
    #pragma unroll
    for (int j = 0; j < 8; ++j) {
        const float a = d[j] - u[j];
        Bv = fmaxf(Bv + a, d[j]);
        A += a;
        S += u[j];
    }

    #pragma unroll
    for (int off = 1; off < 64; off <<= 1) {
        const float Ap = __shfl_up(A, off);
        const float Bp = __shfl_up(Bv, off);
        const float Sp = __shfl_up(S, off);
        if (lane >= off) {
            Bv = fmaxf(Bp + A, Bv);
            A  = A + Ap;
            S  = S + Sp;
        }
    }

    float Aex = __shfl_up(A, 1), Bex = __shfl_up(Bv, 1), Sex = __shfl_up(S, 1);
    if (lane == 0) { Aex = 0.f; Bex = -1e30f; Sex = 0.f; }
    float Q  = fmaxf(Aex, Bex);
    float cu = Sex;

    float rv[8], cv[8];
    #pragma unroll
    for (int j = 0; j < 8; ++j) {
        cu += u[j];
        Q = fmaxf(Q - u[j], 0.f) + d[j];
        rv[j] = Q + cu;
        cv[j] = cu;
    }
    float* rp = Rout  + b * TT + lane * 8;
    float* cp = CUout + b * TT + lane * 8;
    *(float4*)(rp)     = make_float4(rv[0], rv[1], rv[2], rv[3]);
    *(float4*)(rp + 4) = make_float4(rv[4], rv[5], rv[6], rv[7]);
    *(float4*)(cp)     = make_float4(cv[0], cv[1], cv[2], cv[3]);
    *(float4*)(cp + 4) = make_float4(cv[4], cv[5], cv[6], cv[7]);
}

// ---------------------------------------------------------------------------
// K1: fully fused GEMM. out[t,b,e] = sum_i C[t,i] * V[i,b,e] with
//   - A-tile (C) computed IN-KERNEL from R/CU closed form (no C in memory)
//   - B-tile staged from fp32 V with register transpose-convert to bf16
//   - triangular K-loop: m-tile MI only needs k < (MI+1)*128
// 128m x 128n block tile, BK=32, 4 waves (2x2), 64x64 per wave.
// LDS rows stride 40 shorts: frag reads conflict-free, writes <=2-way (free).
// Grid: 1024 blocks x 256 threads; batch b -> XCD b%8 (V_b L2-resident).
// ---------------------------------------------------------------------------
__global__ __launch_bounds__(256) void gemm_fused_kernel(
        const float* __restrict__ V,    // [T(i)][B][E]
        const float* __restrict__ R, const float* __restrict__ CU,
        float* __restrict__ out) {      // [T(t)][B][E]
    const int id   = blockIdx.x;
    const int xcd  = id & 7;
    const int s    = id >> 3;
    const int b    = xcd + 8 * (s & 7);   // b % 8 == xcd
    const int tile = s >> 3;              // 0..15
    const int MI   = tile & 3;
    const int m0   = MI * 128;
    const int n0   = (tile >> 2) * 128;
    const int kiters = 4 * (MI + 1);      // k0 < m0 + 128

    __shared__ __align__(16) unsigned short As[128 * 40];  // [t][i] stride 40
    __shared__ __align__(16) unsigned short Bs[128 * 40];  // [e][i] stride 40
    __shared__ float Rs[TT];

    const int tid  = threadIdx.x;
    const int wave = tid >> 6;
    const int lane = tid & 63;

    // A-fill: thread owns row t_l, 16 contiguous i.
    const int a_t  = tid >> 1;            // 0..127
    const int a_i0 = (tid & 1) * 16;      // 0 or 16
    // B-fill: thread owns 8k x 2e micro-tile.
    const int b_k8 = wave * 8;            // 0..24
    const int b_e2 = lane * 2;            // 0..126
    // Fragments: 2x2 waves, 64x64 per wave.
    const int wm   = (wave >> 1) * 64;
    const int wn   = (wave & 1) * 64;
    const int frow = lane & 15;
    const int quad = lane >> 4;

    // Stage R for this batch into LDS (512 floats).
    ((float2*)Rs)[tid] = ((const float2*)(R + b * TT))[tid];
    const float cu = CU[b * TT + m0 + a_t];
    const float* Vb = V + (size_t)b * EE + n0 + b_e2;   // + k*(BB*EE)
    __syncthreads();

    f32x4 acc[4][4];
    #pragma unroll
    for (int mi = 0; mi < 4; ++mi)
        #pragma unroll
        for (int ni = 0; ni < 4; ++ni)
            acc[mi][ni] = f32x4{0.f, 0.f, 0.f, 0.f};

    for (int kk = 0; kk < kiters; ++kk) {
        const int k0 = kk * 32;

        // ---- A-fill: 16 coeffs from closed form ----
        {
            const int i = k0 + a_i0;
            const float4 r0 = *(const float4*)(Rs + i);
            const float4 r1 = *(const float4*)(Rs + i + 4);
            const float4 r2 = *(const float4*)(Rs + i + 8);
            const float4 r3 = *(const float4*)(Rs + i + 12);
            const float rv[16] = {r0.x, r0.y, r0.z, r0.w, r1.x, r1.y, r1.z, r1.w,
                                  r2.x, r2.y, r2.z, r2.w, r3.x, r3.y, r3.z, r3.w};
            const float prev = (i == 0) ? 0.f : Rs[i - 1];
            float pvp = fminf(fmaxf(prev - cu, 0.f), 1.f);
            float c[16];
            if (k0 < m0) {                    // strictly below diagonal: no mask
                #pragma unroll
                for (int j = 0; j < 16; ++j) {
                    const float pv = fminf(fmaxf(rv[j] - cu, 0.f), 1.f);
                    c[j] = pv - pvp;
                    pvp = pv;
                }
            } else {                          // diagonal tiles: zero for i > t
                const int t = m0 + a_t;
                #pragma unroll
                for (int j = 0; j < 16; ++j) {
                    const float pv = fminf(fmaxf(rv[j] - cu, 0.f), 1.f);
                    c[j] = (i + j <= t) ? (pv - pvp) : 0.f;
                    pvp = pv;
                }
            }
            uint4 w0, w1;
            w0.x = pack_bf16(c[0], c[1]);   w0.y = pack_bf16(c[2], c[3]);
            w0.z = pack_bf16(c[4], c[5]);   w0.w = pack_bf16(c[6], c[7]);
            w1.x = pack_bf16(c[8], c[9]);   w1.y = pack_bf16(c[10], c[11]);
            w1.z = pack_bf16(c[12], c[13]); w1.w = pack_bf16(c[14], c[15]);
            *(uint4*)(As + a_t * 40 + a_i0)     = w0;
            *(uint4*)(As + a_t * 40 + a_i0 + 8) = w1;
        }

        // ---- B-fill: 8k x 2e of V, fp32 -> bf16, register transpose ----
        {
            const float* vp = Vb + (size_t)(k0 + b_k8) * (BB * EE);
            float2 v[8];
            #pragma unroll
            for (int r = 0; r < 8; ++r)
                v[r] = *(const float2*)(vp + (size_t)r * (BB * EE));
            uint4 p0, p1;
            p0.x = pack_bf16(v[0].x, v[1].x); p0.y = pack_bf16(v[2].x, v[3].x);
            p0.z = pack_bf16(v[4].x, v[5].x); p0.w = pack_bf16(v[6].x, v[7].x);
            p1.x = pack_bf16(v[0].y, v[1].y); p1.y = pack_bf16(v[2].y, v[3].y);
            p1.z = pack_bf16(v[4].y, v[5].y); p1.w = pack_bf16(v[6].y, v[7].y);
            *(uint4*)(Bs + b_e2 * 40 + b_k8)       = p0;
            *(uint4*)(Bs + (b_e2 + 1) * 40 + b_k8) = p1;
        }
        __syncthreads();

        bf16x8 af[4], bf[4];
        #pragma unroll
        for (int mi = 0; mi < 4; ++mi)
            af[mi] = *(const bf16x8*)(As + (wm + mi * 16 + frow) * 40 + quad * 8);
        #pragma unroll
        for (int ni = 0; ni < 4; ++ni)
            bf[ni] = *(const bf16x8*)(Bs + (wn + ni * 16 + frow) * 40 + quad * 8);

        #pragma unroll
        for (int mi = 0; mi < 4; ++mi)
            #pragma unroll
            for (int ni = 0; ni < 4; ++ni)
                acc[mi][ni] = __builtin_amdgcn_mfma_f32_16x16x32_bf16(
                    af[mi], bf[ni], acc[mi][ni], 0, 0, 0);
        __syncthreads();
    }

    // Epilogue: C/D layout col=lane&15, row=quad*4+r (m89/m91 verified).
    #pragma unroll
    for (int mi = 0; mi < 4; ++mi) {
        #pragma unroll
        for (int r = 0; r < 4; ++r) {
            const int t = m0 + wm + mi * 16 + quad * 4 + r;
            float* orow = out + ((size_t)t * BB + b) * EE + n0 + wn + frow;
            #pragma unroll
            for (int ni = 0; ni < 4; ++ni)
                orow[ni * 16] = acc[mi][ni][r];
        }
    }
}

extern "C" void kernel_launch(void* const* d_in, const int* in_sizes, int n_in,
                              void* d_out, int out_size, void* d_ws, size_t ws_size,
                              hipStream_t stream) {
    const float* V = (const float*)d_in[0];   // [T,B,E]
    const float* U = (const float*)d_in[1];   // [T,B]
    const float* D = (const float*)d_in[2];   // [T,B]
    float* out = (float*)d_out;               // [T,B,E]

    float* R_ws  = (float*)d_ws;              // [B][T] 128 KB
    float* CU_ws = R_ws + BB * TT;            // [B][T] 128 KB

    scan_kernel<<<dim3(BB), dim3(64), 0, stream>>>(U, D, R_ws, CU_ws);
    gemm_fused_kernel<<<dim3(1024), dim3(256), 0, stream>>>(V, R_ws, CU_ws, out);
}